// Round 9
// baseline (561.912 us; speedup 1.0000x reference)
//
#include <hip/hip_runtime.h>
#include <math.h>

// ---------------- problem constants ----------------
constexpr int M1 = 2000, M2 = 400, BS = 8;
constexpr int AT = M1 + M2;            // 2400
constexpr int NN = BS * AT;            // 19200 nodes
constexpr int E1 = 60000, E2 = 20000, E3 = 20000;
constexpr int ET = E1 + E2 + E3;       // 100000
constexpr int H = 64, F = 64, NG = 50, L = 4, C = 4;
constexpr float CUTOFF = 10.0f;
constexpr float LOG2F_ = 0.6931471805599453f;

constexpr float SMEAR_STEP = 10.0f / 49.0f;
constexpr float SMEAR_COEFF = -12.005f;
constexpr float PI_OVER_CUT = 0.31415926535897932f; // pi/10

constexpr int NBLK = (ET + 255) / 256;  // 391 blocks in count/fill passes

// Edge-MLP lerp table: NT points over [0,CUTOFF] per (g,c,l) slice (48 slices).
constexpr int NT = 512;
constexpr float DSCALE = (float)(NT - 1) / CUTOFF;   // 51.1

// GEMM tiling
constexpr int TILE_M = 32;
constexpr int MT = NN / TILE_M;        // 600 row-tiles (75 per structure: aligned)

// ---------------- workspace layout (bytes) ----------------
constexpr size_t O_H     = 0;                           // h   [NN,64] f32 (4.9MB)
constexpr size_t O_XG    = O_H   + (size_t)NN * 64 * 4; // xg  [3][AT][BS][64] b-major
constexpr size_t O_AGG   = O_XG  + (size_t)3 * NN * 64 * 4; // agg3 [3,NN,64] n-major
constexpr size_t O_TAB   = O_AGG + (size_t)3 * NN * 64 * 4; // tab [48,NT,64] (6.3MB)
constexpr size_t O_EDATA = O_TAB + (size_t)48 * NT * 64 * 4; // edata [ET] int4 (1.6MB)
constexpr size_t O_INT   = O_EDATA + (size_t)ET * 16;
// int region (element offsets from O_INT):
constexpr int I_DEG  = 0;      // [3*AT] zeroed
constexpr int I_CUR  = 7200;   // [3*AT] zeroed
constexpr int I_ZEND = 14400;
constexpr int I_BASE = 14400;  // [3*(AT+1)] = 7203, reserve 7216

__device__ inline float sspf(float x) {
    return fmaxf(x, 0.0f) + log1pf(expf(-fabsf(x))) - LOG2F_;
}
__device__ inline float sspf_fast(float x) {
    float t = __expf(-fabsf(x));
    return fmaxf(x, 0.0f) + __logf(1.0f + t) - LOG2F_;
}

__device__ inline int graph_off(int g) { return g == 0 ? 0 : (g == 1 ? E1 : E1 + E2); }

__device__ inline void edge_decode(int idx, int& g, int& e,
                                   const int* ei1, const int* ei2, const int* ei3,
                                   const int* c1, const int* c2, const int* c3,
                                   const int*& ei, const int*& cl) {
    if (idx < E1)            { g = 0; e = idx;           ei = ei1; cl = c1; }
    else if (idx < E1 + E2)  { g = 1; e = idx - E1;      ei = ei2; cl = c2; }
    else                     { g = 2; e = idx - E1 - E2; ei = ei3; cl = c3; }
}

// ---------------- setup kernels ----------------
__global__ void k_init_h(const int* __restrict__ sites, const int* __restrict__ sites_p,
                         const float* __restrict__ emb_w, const float* __restrict__ emb_p_w,
                         float* __restrict__ h) {
    int idx = blockIdx.x * blockDim.x + threadIdx.x;
    if (idx >= NN * 64) return;
    int f = idx & 63;
    int n = idx >> 6;
    int b = n / AT;
    int i = n - b * AT;
    float v;
    if (i < M1) v = emb_w[sites[b * M1 + i] * H + f];
    else        v = emb_p_w[sites_p[b * M2 + (i - M1)] * H + f];
    h[idx] = v;
}

__global__ void k_count(const int* __restrict__ ei1, const int* __restrict__ ei2,
                        const int* __restrict__ ei3, const int* __restrict__ c1,
                        const int* __restrict__ c2, const int* __restrict__ c3,
                        int* __restrict__ deg) {
    int idx = blockIdx.x * blockDim.x + threadIdx.x;
    if (idx >= ET) return;
    int g, e; const int* ei; const int* cl;
    edge_decode(idx, g, e, ei1, ei2, ei3, c1, c2, c3, ei, cl);
    atomicAdd(&deg[g * AT + ei[2 * e + 1]], 1);
}

__global__ void k_scan(const int* __restrict__ deg, int* __restrict__ base) {
    const int T = 256, CH = 10; // 2560 >= 2400
    int t = threadIdx.x;
    __shared__ int lsum[T];
    int g = blockIdx.x;
    int loc[CH];
    int s = 0;
    #pragma unroll
    for (int i = 0; i < CH; i++) {
        int idx = t * CH + i;
        int v = (idx < AT) ? deg[g * AT + idx] : 0;
        loc[i] = s;
        s += v;
    }
    lsum[t] = s;
    __syncthreads();
    for (int off = 1; off < T; off <<= 1) {
        int v = 0;
        if (t >= off) v = lsum[t - off];
        __syncthreads();
        lsum[t] += v;
        __syncthreads();
    }
    int tb = lsum[t] - s;
    #pragma unroll
    for (int i = 0; i < CH; i++) {
        int idx = t * CH + i;
        if (idx < AT) base[g * (AT + 1) + idx] = tb + loc[i];
    }
    if (t == T - 1) base[g * (AT + 1) + AT] = lsum[T - 1];
}

__global__ void k_fill(const int* __restrict__ ei1, const int* __restrict__ ei2,
                       const int* __restrict__ ei3, const int* __restrict__ c1,
                       const int* __restrict__ c2, const int* __restrict__ c3,
                       const float* __restrict__ ew1, const float* __restrict__ ew2,
                       const float* __restrict__ ew3,
                       const int* __restrict__ base, int* __restrict__ cur,
                       int4* __restrict__ edata) {
    int idx = blockIdx.x * blockDim.x + threadIdx.x;
    if (idx >= ET) return;
    int g, e; const int* ei; const int* cl;
    edge_decode(idx, g, e, ei1, ei2, ei3, c1, c2, c3, ei, cl);
    const float* ew = (g == 0) ? ew1 : (g == 1 ? ew2 : ew3);
    int dst = ei[2 * e + 1];
    int src = ei[2 * e];
    int p = base[g * (AT + 1) + dst] + atomicAdd(&cur[g * AT + dst], 1);
    float t = ew[e] * DSCALE;
    int i0 = min((int)t, NT - 2);
    float fr = t - (float)i0;
    int cb = cl[e] * (L * NT) + i0;
    edata[graph_off(g) + p] = make_int4(src, cb, __float_as_int(fr), 0);
}

// ---------------- edge-MLP table build ----------------
__global__ __launch_bounds__(256) void k_table(
    const float* __restrict__ mlp_w1, const float* __restrict__ mlp_b1,
    const float* __restrict__ mlp_w2, const float* __restrict__ mlp_b2,
    float* __restrict__ tab) {
    const int lane = threadIdx.x & 63;
    int w = blockIdx.x * 4 + (threadIdx.x >> 6);
    int s = w >> 9;          // / NT(512) points per slice
    int p = w & (NT - 1);
    int l = s % L;
    int gc = s / L;
    int c = gc % C;
    int g = gc / C;
    float d = (float)p * (CUTOFF / (float)(NT - 1));

    size_t wb = (size_t)((l * 3 + g) * C + c);
    const float* w1 = mlp_w1 + wb * NG * F;
    const float* w2 = mlp_w2 + wb * F * F;
    float w1c[NG], w2c[F];
    #pragma unroll
    for (int k = 0; k < NG; k++) w1c[k] = w1[k * F + lane];
    #pragma unroll
    for (int k = 0; k < F; k++) w2c[k] = w2[k * F + lane];
    float b1c = mlp_b1[wb * F + lane];
    float b2c = mlp_b2[wb * F + lane];

    float dd = d - (float)lane * SMEAR_STEP;
    float av = (lane < NG) ? __expf(SMEAR_COEFF * dd * dd) : 0.0f;
    float acc = b1c;
    #pragma unroll
    for (int k = 0; k < NG; k++) acc = fmaf(__shfl(av, k), w1c[k], acc);
    float t = sspf_fast(acc);
    float acc2 = b2c;
    #pragma unroll
    for (int j = 0; j < F; j++) acc2 = fmaf(__shfl(t, j), w2c[j], acc2);
    float ccut = 0.5f * (__cosf(d * PI_OVER_CUT) + 1.0f);
    tab[((size_t)s * NT + p) * 64 + lane] = acc2 * ccut;
}

// ---------------- LDS-tiled GEMM machinery ----------------
// 256 threads; tile M=32 x N=64, K=64 staged. thread (cg=t&15, rg=t>>4)
// computes rows {rg*2, rg*2+1} x cols [cg*4, cg*4+4). Rows padded to 68.

__device__ inline void fma4(float acc[4], float a, const float4 b) {
    acc[0] = fmaf(a, b.x, acc[0]);
    acc[1] = fmaf(a, b.y, acc[1]);
    acc[2] = fmaf(a, b.z, acc[2]);
    acc[3] = fmaf(a, b.w, acc[3]);
}

__device__ inline void stage_A(const float* __restrict__ gA, float (*As)[68], int t) {
    #pragma unroll
    for (int i = 0; i < 2; i++) {
        int v = t + i * 256;            // 512 float4s = 32 rows x 16
        int r = v >> 4, c4 = (v & 15) * 4;
        *(float4*)&As[r][c4] = *(const float4*)(gA + (size_t)r * 64 + c4);
    }
}
__device__ inline void stage_B(const float* __restrict__ gB, float (*Bs)[68], int t) {
    #pragma unroll
    for (int i = 0; i < 4; i++) {
        int v = t + i * 256;            // 1024 float4s = 64 rows x 16
        int r = v >> 4, c4 = (v & 15) * 4;
        *(float4*)&Bs[r][c4] = *(const float4*)(gB + (size_t)r * 64 + c4);
    }
}
__device__ inline void gemm_tile(const float (*As)[68], const float (*Bs)[68],
                                 int r0, int c0, float acc0[4], float acc1[4]) {
    #pragma unroll 4
    for (int k0 = 0; k0 < 64; k0 += 4) {
        float4 a0 = *(const float4*)&As[r0][k0];
        float4 a1 = *(const float4*)&As[r0 + 1][k0];
        float4 b0 = *(const float4*)&Bs[k0][c0];
        float4 b1 = *(const float4*)&Bs[k0 + 1][c0];
        float4 b2 = *(const float4*)&Bs[k0 + 2][c0];
        float4 b3 = *(const float4*)&Bs[k0 + 3][c0];
        fma4(acc0, a0.x, b0); fma4(acc0, a0.y, b1);
        fma4(acc0, a0.z, b2); fma4(acc0, a0.w, b3);
        fma4(acc1, a1.x, b0); fma4(acc1, a1.y, b1);
        fma4(acc1, a1.z, b2); fma4(acc1, a1.w, b3);
    }
}

// xg store in b-major layout: xg[((g*AT + i)*BS + b)*64 + c]
__device__ inline void store_xg(float* __restrict__ xg, int g, int n, int c0,
                                const float acc[4]) {
    int b = n / AT;
    int i = n - b * AT;
    float* out = xg + (((size_t)g * AT + i) * BS + b) * 64 + c0;
    *(float4*)out = make_float4(acc[0], acc[1], acc[2], acc[3]);
}

// xg[g] = h @ conv_w1[l,g]; grid 3*MT
__global__ __launch_bounds__(256) void k_lin1t(
    const float* __restrict__ h, const float* __restrict__ conv_w1,
    float* __restrict__ xg, int l) {
    __shared__ float As[TILE_M][68];
    __shared__ float Bs[64][68];
    int t = threadIdx.x;
    int g = blockIdx.x / MT;
    int tile = blockIdx.x - g * MT;
    stage_A(h + (size_t)tile * TILE_M * 64, As, t);
    stage_B(conv_w1 + (size_t)(l * 3 + g) * 64 * 64, Bs, t);
    __syncthreads();
    int cg = t & 15, rg = t >> 4;
    int c0 = cg * 4, r0 = rg * 2;
    float acc0[4] = {0, 0, 0, 0}, acc1[4] = {0, 0, 0, 0};
    gemm_tile(As, Bs, r0, c0, acc0, acc1);
    int n0 = tile * TILE_M;
    store_xg(xg, g, n0 + r0, c0, acc0);
    store_xg(xg, g, n0 + r0 + 1, c0, acc1);
}

// Per-(g,tile): h += ssp(agg_g@cw2 + cb2)@bw_g + bb_g  (fp32 atomics).
// Both weight matrices staged up-front into separate LDS buffers -> 2 barriers.
// grid 3*MT = 1800 blocks.
__global__ __launch_bounds__(256) void k_layerA(
    const float* __restrict__ agg3, const float* __restrict__ conv_w2,
    const float* __restrict__ conv_b2, const float* __restrict__ blk_w,
    const float* __restrict__ blk_b, float* __restrict__ h, int l) {
    __shared__ float As[TILE_M][68];
    __shared__ float Bs[64][68];
    __shared__ float B2[64][68];
    __shared__ float Ts[TILE_M][68];
    int t = threadIdx.x;
    int g = blockIdx.x / MT;
    int tile = blockIdx.x - g * MT;
    size_t pb = (size_t)(l * 3 + g);
    stage_A(agg3 + ((size_t)g * NN + (size_t)tile * TILE_M) * 64, As, t);
    stage_B(conv_w2 + pb * 4096, Bs, t);
    stage_B(blk_w + pb * 4096, B2, t);
    __syncthreads();
    int cg = t & 15, rg = t >> 4;
    int c0 = cg * 4, r0 = rg * 2;
    float4 bias = *(const float4*)(conv_b2 + pb * 64 + c0);
    float a0[4] = {bias.x, bias.y, bias.z, bias.w};
    float a1[4] = {bias.x, bias.y, bias.z, bias.w};
    gemm_tile(As, Bs, r0, c0, a0, a1);
    *(float4*)&Ts[r0][c0] =
        make_float4(sspf(a0[0]), sspf(a0[1]), sspf(a0[2]), sspf(a0[3]));
    *(float4*)&Ts[r0 + 1][c0] =
        make_float4(sspf(a1[0]), sspf(a1[1]), sspf(a1[2]), sspf(a1[3]));
    __syncthreads();
    float4 bb = *(const float4*)(blk_b + pb * 64 + c0);
    float b0[4] = {bb.x, bb.y, bb.z, bb.w};
    float b1[4] = {bb.x, bb.y, bb.z, bb.w};
    gemm_tile(Ts, B2, r0, c0, b0, b1);
    float* hp = h + (size_t)tile * TILE_M * 64;
    #pragma unroll
    for (int j = 0; j < 4; j++) {
        atomicAdd(hp + (size_t)r0 * 64 + c0 + j, b0[j]);
        atomicAdd(hp + (size_t)(r0 + 1) * 64 + c0 + j, b1[j]);
    }
}

// ---------------- aggregation ----------------
// One wave per (g,dst); per edge: one int4 record + table lerp; 8 batches in
// registers; b-major xg layout makes the 8-batch gather one 2KB contiguous run.
__global__ __launch_bounds__(256) void k_agg(
    const int4* __restrict__ edata, const int* __restrict__ base,
    const float* __restrict__ xg, const float* __restrict__ tab,
    float* __restrict__ agg3, int l) {
    const int lane = threadIdx.x & 63;
    int w = blockIdx.x * 4 + (threadIdx.x >> 6); // 0..7199
    int g = w / AT;
    int dst = w - g * AT;
    const int4* ed = edata + graph_off(g);
    int s = base[g * (AT + 1) + dst];
    int e = base[g * (AT + 1) + dst + 1];
    const float* tg = tab + ((size_t)g * C * L * NT) * 64 + (size_t)l * NT * 64;
    const float* xgg = xg + (size_t)g * AT * BS * 64;
    float acc[BS];
    #pragma unroll
    for (int b = 0; b < BS; b++) acc[b] = 0.0f;
    int i = s;
    for (; i + 2 <= e; i += 2) {
        int4 mA = ed[i], mB = ed[i + 1];
        const float* rA = tg + (size_t)mA.y * 64;
        const float* rB = tg + (size_t)mB.y * 64;
        float frA = __int_as_float(mA.z), frB = __int_as_float(mB.z);
        float rA0 = rA[lane], rA1 = rA[64 + lane];
        float rB0 = rB[lane], rB1 = rB[64 + lane];
        float wvA = fmaf(frA, rA1 - rA0, rA0);
        float wvB = fmaf(frB, rB1 - rB0, rB0);
        const float* xbA = xgg + (size_t)mA.x * (BS * 64) + lane;
        const float* xbB = xgg + (size_t)mB.x * (BS * 64) + lane;
        #pragma unroll
        for (int b = 0; b < BS; b++) {
            acc[b] = fmaf(xbA[b * 64], wvA, acc[b]);
            acc[b] = fmaf(xbB[b * 64], wvB, acc[b]);
        }
    }
    if (i < e) {
        int4 m = ed[i];
        const float* r = tg + (size_t)m.y * 64;
        float fr = __int_as_float(m.z);
        float r0 = r[lane], r1 = r[64 + lane];
        float wv = fmaf(fr, r1 - r0, r0);
        const float* xb = xgg + (size_t)m.x * (BS * 64) + lane;
        #pragma unroll
        for (int b = 0; b < BS; b++)
            acc[b] = fmaf(xb[b * 64], wv, acc[b]);
    }
    float* ao = agg3 + ((size_t)g * NN + dst) * F + lane;
    #pragma unroll
    for (int b = 0; b < BS; b++) ao[(size_t)b * AT * F] = acc[b];
}

// Readout: o[b] = sum_pore h . weff + M2*(b1.W2 + b2), weff = W1@W2
__global__ void k_read(const float* __restrict__ h,
                       const float* __restrict__ w1, const float* __restrict__ b1,
                       const float* __restrict__ w2, const float* __restrict__ b2,
                       float* __restrict__ out) {
    int b = blockIdx.x;
    int lane = threadIdx.x & 63;
    int wv = threadIdx.x >> 6;
    __shared__ float part[4];
    float weff = 0.0f;
    #pragma unroll
    for (int j = 0; j < H / 2; j++) weff = fmaf(w1[lane * (H / 2) + j], w2[j], weff);
    float acc = 0.0f;
    for (int i = wv * (M2 / 4); i < (wv + 1) * (M2 / 4); i++)
        acc += h[((size_t)b * AT + M1 + i) * H + lane];
    float v = acc * weff;
    for (int off = 32; off; off >>= 1) v += __shfl_xor(v, off);
    if (lane == 0) part[wv] = v;
    __syncthreads();
    if (threadIdx.x == 0) {
        float bias = b2[0];
        for (int j = 0; j < H / 2; j++) bias = fmaf(b1[j], w2[j], bias);
        out[b] = part[0] + part[1] + part[2] + part[3] + (float)M2 * bias;
    }
}

// ---------------- launcher ----------------
extern "C" void kernel_launch(void* const* d_in, const int* in_sizes, int n_in,
                              void* d_out, int out_size, void* d_ws, size_t ws_size,
                              hipStream_t stream) {
    const int* sites   = (const int*)d_in[0];
    const int* sites_p = (const int*)d_in[1];
    const int* ei1 = (const int*)d_in[2];
    const float* ew1 = (const float*)d_in[3];
    const int* c1 = (const int*)d_in[4];
    const int* ei2 = (const int*)d_in[5];
    const float* ew2 = (const float*)d_in[6];
    const int* c2 = (const int*)d_in[7];
    const int* ei3 = (const int*)d_in[8];
    const float* ew3 = (const float*)d_in[9];
    const int* c3 = (const int*)d_in[10];
    const float* emb_w   = (const float*)d_in[11];
    const float* emb_p_w = (const float*)d_in[12];
    const float* mlp_w1 = (const float*)d_in[13];
    const float* mlp_b1 = (const float*)d_in[14];
    const float* mlp_w2 = (const float*)d_in[15];
    const float* mlp_b2 = (const float*)d_in[16];
    const float* conv_w1 = (const float*)d_in[17];
    const float* conv_w2 = (const float*)d_in[18];
    const float* conv_b2 = (const float*)d_in[19];
    const float* blk_w = (const float*)d_in[20];
    const float* blk_b = (const float*)d_in[21];
    const float* out_w1 = (const float*)d_in[22];
    const float* out_b1 = (const float*)d_in[23];
    const float* out_w2 = (const float*)d_in[24];
    const float* out_b2 = (const float*)d_in[25];

    char* ws = (char*)d_ws;
    float* h    = (float*)(ws + O_H);
    float* xg   = (float*)(ws + O_XG);
    float* agg3 = (float*)(ws + O_AGG);
    float* tab  = (float*)(ws + O_TAB);
    int4*  edata = (int4*)(ws + O_EDATA);
    int* ip    = (int*)(ws + O_INT);
    int* deg   = ip + I_DEG;
    int* cur   = ip + I_CUR;
    int* ibase = ip + I_BASE;

    hipMemsetAsync(ip, 0, (size_t)I_ZEND * sizeof(int), stream);

    k_table<<<48 * NT / 4, 256, 0, stream>>>(mlp_w1, mlp_b1, mlp_w2, mlp_b2, tab);
    k_init_h<<<(NN * 64 + 255) / 256, 256, 0, stream>>>(sites, sites_p, emb_w, emb_p_w, h);
    k_count<<<NBLK, 256, 0, stream>>>(ei1, ei2, ei3, c1, c2, c3, deg);
    k_scan<<<3, 256, 0, stream>>>(deg, ibase);
    k_fill<<<NBLK, 256, 0, stream>>>(ei1, ei2, ei3, c1, c2, c3, ew1, ew2, ew3,
                                     ibase, cur, edata);

    k_lin1t<<<3 * MT, 256, 0, stream>>>(h, conv_w1, xg, 0);
    for (int l = 0; l < L; l++) {
        k_agg<<<3 * AT / 4, 256, 0, stream>>>(edata, ibase, xg, tab, agg3, l);
        k_layerA<<<3 * MT, 256, 0, stream>>>(agg3, conv_w2, conv_b2, blk_w, blk_b,
                                             h, l);
        if (l < L - 1)
            k_lin1t<<<3 * MT, 256, 0, stream>>>(h, conv_w1, xg, l + 1);
    }
    k_read<<<BS, 256, 0, stream>>>(h, out_w1, out_b1, out_w2, out_b2, (float*)d_out);
}

// Round 10
// 478.295 us; speedup vs baseline: 1.1748x; 1.1748x over previous
//
#include <hip/hip_runtime.h>
#include <math.h>

// ---------------- problem constants ----------------
constexpr int M1 = 2000, M2 = 400, BS = 8;
constexpr int AT = M1 + M2;            // 2400
constexpr int NN = BS * AT;            // 19200 nodes
constexpr int E1 = 60000, E2 = 20000, E3 = 20000;
constexpr int ET = E1 + E2 + E3;       // 100000
constexpr int H = 64, F = 64, NG = 50, L = 4, C = 4;
constexpr float CUTOFF = 10.0f;
constexpr float LOG2F_ = 0.6931471805599453f;

constexpr float SMEAR_STEP = 10.0f / 49.0f;
constexpr float SMEAR_COEFF = -12.005f;
constexpr float PI_OVER_CUT = 0.31415926535897932f; // pi/10

constexpr int NBLK = (ET + 255) / 256;

// Edge-MLP lerp table: NT points over [0,CUTOFF] per (g,c,l) slice (48 slices).
constexpr int NT = 512;
constexpr float DSCALE = (float)(NT - 1) / CUTOFF;   // 51.1

// GEMM tiling
constexpr int TILE_M = 32;
constexpr int MT = NN / TILE_M;        // 600 row-tiles

// ---------------- workspace layout (bytes) ----------------
constexpr size_t O_HA    = 0;                            // hA [NN,64] (4.9MB)
constexpr size_t O_HB    = O_HA  + (size_t)NN * 64 * 4;  // hB [NN,64] (4.9MB)
constexpr size_t O_XG    = O_HB  + (size_t)NN * 64 * 4;  // xg [3][AT][BS][64] b-major
constexpr size_t O_AGG   = O_XG  + (size_t)3 * NN * 64 * 4; // agg3 [3,NN,64]
constexpr size_t O_DG    = O_AGG + (size_t)3 * NN * 64 * 4; // dg [3,NN,64]
constexpr size_t O_TAB   = O_DG  + (size_t)3 * NN * 64 * 4; // tab [48,NT,64] (6.3MB)
constexpr size_t O_EDATA = O_TAB + (size_t)48 * NT * 64 * 4; // edata [ET] int4
constexpr size_t O_INT   = O_EDATA + (size_t)ET * 16;
constexpr int I_DEG  = 0;      // [3*AT] zeroed
constexpr int I_CUR  = 7200;   // [3*AT] zeroed
constexpr int I_ZEND = 14400;
constexpr int I_BASE = 14400;  // [3*(AT+1)]

__device__ inline float sspf(float x) {
    return fmaxf(x, 0.0f) + log1pf(expf(-fabsf(x))) - LOG2F_;
}
__device__ inline float sspf_fast(float x) {
    float t = __expf(-fabsf(x));
    return fmaxf(x, 0.0f) + __logf(1.0f + t) - LOG2F_;
}

__device__ inline int graph_off(int g) { return g == 0 ? 0 : (g == 1 ? E1 : E1 + E2); }

__device__ inline void edge_decode(int idx, int& g, int& e,
                                   const int* ei1, const int* ei2, const int* ei3,
                                   const int* c1, const int* c2, const int* c3,
                                   const int*& ei, const int*& cl) {
    if (idx < E1)            { g = 0; e = idx;           ei = ei1; cl = c1; }
    else if (idx < E1 + E2)  { g = 1; e = idx - E1;      ei = ei2; cl = c2; }
    else                     { g = 2; e = idx - E1 - E2; ei = ei3; cl = c3; }
}

// ---------------- setup kernels ----------------
__global__ void k_init_h(const int* __restrict__ sites, const int* __restrict__ sites_p,
                         const float* __restrict__ emb_w, const float* __restrict__ emb_p_w,
                         float* __restrict__ h) {
    int idx = blockIdx.x * blockDim.x + threadIdx.x;
    if (idx >= NN * 64) return;
    int f = idx & 63;
    int n = idx >> 6;
    int b = n / AT;
    int i = n - b * AT;
    float v;
    if (i < M1) v = emb_w[sites[b * M1 + i] * H + f];
    else        v = emb_p_w[sites_p[b * M2 + (i - M1)] * H + f];
    h[idx] = v;
}

__global__ void k_count(const int* __restrict__ ei1, const int* __restrict__ ei2,
                        const int* __restrict__ ei3, const int* __restrict__ c1,
                        const int* __restrict__ c2, const int* __restrict__ c3,
                        int* __restrict__ deg) {
    int idx = blockIdx.x * blockDim.x + threadIdx.x;
    if (idx >= ET) return;
    int g, e; const int* ei; const int* cl;
    edge_decode(idx, g, e, ei1, ei2, ei3, c1, c2, c3, ei, cl);
    atomicAdd(&deg[g * AT + ei[2 * e + 1]], 1);
}

__global__ void k_scan(const int* __restrict__ deg, int* __restrict__ base) {
    const int T = 256, CH = 10;
    int t = threadIdx.x;
    __shared__ int lsum[T];
    int g = blockIdx.x;
    int loc[CH];
    int s = 0;
    #pragma unroll
    for (int i = 0; i < CH; i++) {
        int idx = t * CH + i;
        int v = (idx < AT) ? deg[g * AT + idx] : 0;
        loc[i] = s;
        s += v;
    }
    lsum[t] = s;
    __syncthreads();
    for (int off = 1; off < T; off <<= 1) {
        int v = 0;
        if (t >= off) v = lsum[t - off];
        __syncthreads();
        lsum[t] += v;
        __syncthreads();
    }
    int tb = lsum[t] - s;
    #pragma unroll
    for (int i = 0; i < CH; i++) {
        int idx = t * CH + i;
        if (idx < AT) base[g * (AT + 1) + idx] = tb + loc[i];
    }
    if (t == T - 1) base[g * (AT + 1) + AT] = lsum[T - 1];
}

__global__ void k_fill(const int* __restrict__ ei1, const int* __restrict__ ei2,
                       const int* __restrict__ ei3, const int* __restrict__ c1,
                       const int* __restrict__ c2, const int* __restrict__ c3,
                       const float* __restrict__ ew1, const float* __restrict__ ew2,
                       const float* __restrict__ ew3,
                       const int* __restrict__ base, int* __restrict__ cur,
                       int4* __restrict__ edata) {
    int idx = blockIdx.x * blockDim.x + threadIdx.x;
    if (idx >= ET) return;
    int g, e; const int* ei; const int* cl;
    edge_decode(idx, g, e, ei1, ei2, ei3, c1, c2, c3, ei, cl);
    const float* ew = (g == 0) ? ew1 : (g == 1 ? ew2 : ew3);
    int dst = ei[2 * e + 1];
    int src = ei[2 * e];
    int p = base[g * (AT + 1) + dst] + atomicAdd(&cur[g * AT + dst], 1);
    float t = ew[e] * DSCALE;
    int i0 = min((int)t, NT - 2);
    float fr = t - (float)i0;
    int cb = cl[e] * (L * NT) + i0;
    edata[graph_off(g) + p] = make_int4(src, cb, __float_as_int(fr), 0);
}

// ---------------- edge-MLP table build ----------------
__global__ __launch_bounds__(256) void k_table(
    const float* __restrict__ mlp_w1, const float* __restrict__ mlp_b1,
    const float* __restrict__ mlp_w2, const float* __restrict__ mlp_b2,
    float* __restrict__ tab) {
    const int lane = threadIdx.x & 63;
    int w = blockIdx.x * 4 + (threadIdx.x >> 6);
    int s = w >> 9;
    int p = w & (NT - 1);
    int l = s % L;
    int gc = s / L;
    int c = gc % C;
    int g = gc / C;
    float d = (float)p * (CUTOFF / (float)(NT - 1));

    size_t wb = (size_t)((l * 3 + g) * C + c);
    const float* w1 = mlp_w1 + wb * NG * F;
    const float* w2 = mlp_w2 + wb * F * F;
    float w1c[NG], w2c[F];
    #pragma unroll
    for (int k = 0; k < NG; k++) w1c[k] = w1[k * F + lane];
    #pragma unroll
    for (int k = 0; k < F; k++) w2c[k] = w2[k * F + lane];
    float b1c = mlp_b1[wb * F + lane];
    float b2c = mlp_b2[wb * F + lane];

    float dd = d - (float)lane * SMEAR_STEP;
    float av = (lane < NG) ? __expf(SMEAR_COEFF * dd * dd) : 0.0f;
    float acc = b1c;
    #pragma unroll
    for (int k = 0; k < NG; k++) acc = fmaf(__shfl(av, k), w1c[k], acc);
    float t = sspf_fast(acc);
    float acc2 = b2c;
    #pragma unroll
    for (int j = 0; j < F; j++) acc2 = fmaf(__shfl(t, j), w2c[j], acc2);
    float ccut = 0.5f * (__cosf(d * PI_OVER_CUT) + 1.0f);
    tab[((size_t)s * NT + p) * 64 + lane] = acc2 * ccut;
}

// ---------------- LDS-tiled GEMM machinery ----------------
__device__ inline void fma4(float acc[4], float a, const float4 b) {
    acc[0] = fmaf(a, b.x, acc[0]);
    acc[1] = fmaf(a, b.y, acc[1]);
    acc[2] = fmaf(a, b.z, acc[2]);
    acc[3] = fmaf(a, b.w, acc[3]);
}

__device__ inline void stage_A(const float* __restrict__ gA, float (*As)[68], int t) {
    #pragma unroll
    for (int i = 0; i < 2; i++) {
        int v = t + i * 256;
        int r = v >> 4, c4 = (v & 15) * 4;
        *(float4*)&As[r][c4] = *(const float4*)(gA + (size_t)r * 64 + c4);
    }
}
__device__ inline void stage_B(const float* __restrict__ gB, float (*Bs)[68], int t) {
    #pragma unroll
    for (int i = 0; i < 4; i++) {
        int v = t + i * 256;
        int r = v >> 4, c4 = (v & 15) * 4;
        *(float4*)&Bs[r][c4] = *(const float4*)(gB + (size_t)r * 64 + c4);
    }
}
__device__ inline void gemm_tile(const float (*As)[68], const float (*Bs)[68],
                                 int r0, int c0, float acc0[4], float acc1[4]) {
    #pragma unroll 4
    for (int k0 = 0; k0 < 64; k0 += 4) {
        float4 a0 = *(const float4*)&As[r0][k0];
        float4 a1 = *(const float4*)&As[r0 + 1][k0];
        float4 b0 = *(const float4*)&Bs[k0][c0];
        float4 b1 = *(const float4*)&Bs[k0 + 1][c0];
        float4 b2 = *(const float4*)&Bs[k0 + 2][c0];
        float4 b3 = *(const float4*)&Bs[k0 + 3][c0];
        fma4(acc0, a0.x, b0); fma4(acc0, a0.y, b1);
        fma4(acc0, a0.z, b2); fma4(acc0, a0.w, b3);
        fma4(acc1, a1.x, b0); fma4(acc1, a1.y, b1);
        fma4(acc1, a1.z, b2); fma4(acc1, a1.w, b3);
    }
}

// xg store in b-major layout: xg[((g*AT + i)*BS + b)*64 + c]
__device__ inline void store_xg(float* __restrict__ xg, int g, int n, int c0,
                                const float acc[4]) {
    int b = n / AT;
    int i = n - b * AT;
    float* out = xg + (((size_t)g * AT + i) * BS + b) * 64 + c0;
    *(float4*)out = make_float4(acc[0], acc[1], acc[2], acc[3]);
}

// xg[g] = h @ conv_w1[0,g]; grid 3*MT (initial layer only)
__global__ __launch_bounds__(256) void k_lin1t(
    const float* __restrict__ h, const float* __restrict__ conv_w1,
    float* __restrict__ xg, int l) {
    __shared__ float As[TILE_M][68];
    __shared__ float Bs[64][68];
    int t = threadIdx.x;
    int g = blockIdx.x / MT;
    int tile = blockIdx.x - g * MT;
    stage_A(h + (size_t)tile * TILE_M * 64, As, t);
    stage_B(conv_w1 + (size_t)(l * 3 + g) * 64 * 64, Bs, t);
    __syncthreads();
    int cg = t & 15, rg = t >> 4;
    int c0 = cg * 4, r0 = rg * 2;
    float acc0[4] = {0, 0, 0, 0}, acc1[4] = {0, 0, 0, 0};
    gemm_tile(As, Bs, r0, c0, acc0, acc1);
    int n0 = tile * TILE_M;
    store_xg(xg, g, n0 + r0, c0, acc0);
    store_xg(xg, g, n0 + r0 + 1, c0, acc1);
}

// Per-(g,tile): dg[g] = ssp(agg_g@cw2 + cb2)@bw_g + bb_g  (plain stores).
// grid 3*MT = 1800 blocks, 2 barriers.
__global__ __launch_bounds__(256) void k_layerA(
    const float* __restrict__ agg3, const float* __restrict__ conv_w2,
    const float* __restrict__ conv_b2, const float* __restrict__ blk_w,
    const float* __restrict__ blk_b, float* __restrict__ dg, int l) {
    __shared__ float As[TILE_M][68];
    __shared__ float Bs[64][68];
    __shared__ float B2[64][68];
    __shared__ float Ts[TILE_M][68];
    int t = threadIdx.x;
    int g = blockIdx.x / MT;
    int tile = blockIdx.x - g * MT;
    size_t pb = (size_t)(l * 3 + g);
    stage_A(agg3 + ((size_t)g * NN + (size_t)tile * TILE_M) * 64, As, t);
    stage_B(conv_w2 + pb * 4096, Bs, t);
    stage_B(blk_w + pb * 4096, B2, t);
    __syncthreads();
    int cg = t & 15, rg = t >> 4;
    int c0 = cg * 4, r0 = rg * 2;
    float4 bias = *(const float4*)(conv_b2 + pb * 64 + c0);
    float a0[4] = {bias.x, bias.y, bias.z, bias.w};
    float a1[4] = {bias.x, bias.y, bias.z, bias.w};
    gemm_tile(As, Bs, r0, c0, a0, a1);
    *(float4*)&Ts[r0][c0] =
        make_float4(sspf(a0[0]), sspf(a0[1]), sspf(a0[2]), sspf(a0[3]));
    *(float4*)&Ts[r0 + 1][c0] =
        make_float4(sspf(a1[0]), sspf(a1[1]), sspf(a1[2]), sspf(a1[3]));
    __syncthreads();
    float4 bb = *(const float4*)(blk_b + pb * 64 + c0);
    float b0[4] = {bb.x, bb.y, bb.z, bb.w};
    float b1[4] = {bb.x, bb.y, bb.z, bb.w};
    gemm_tile(Ts, B2, r0, c0, b0, b1);
    float* dp = dg + ((size_t)g * NN + (size_t)tile * TILE_M) * 64;
    *(float4*)(dp + (size_t)r0 * 64 + c0)       = make_float4(b0[0], b0[1], b0[2], b0[3]);
    *(float4*)(dp + (size_t)(r0 + 1) * 64 + c0) = make_float4(b1[0], b1[1], b1[2], b1[3]);
}

// Fused h-update + next-layer lin1. grid 3*MT (last layer: MT, g=0 only).
// Each block redundantly computes h' = hIn + dg0+dg1+dg2 for its tile (L2-hot);
// g==0 blocks store h' to hOut (ping-pong -> no same-dispatch race);
// then xg_g = h' @ conv_w1[lnext,g].
__global__ __launch_bounds__(256) void k_lin1f(
    const float* __restrict__ hIn, float* __restrict__ hOut,
    const float* __restrict__ dg, const float* __restrict__ conv_w1,
    float* __restrict__ xg, int lnext, int last) {
    __shared__ float As[TILE_M][68];
    __shared__ float Bs[64][68];
    int t = threadIdx.x;
    int g, tile;
    if (last) { g = 0; tile = blockIdx.x; }
    else      { g = blockIdx.x / MT; tile = blockIdx.x - g * MT; }
    size_t off = (size_t)tile * TILE_M * 64;
    #pragma unroll
    for (int i = 0; i < 2; i++) {
        int v = t + i * 256;
        int r = v >> 4, c4 = (v & 15) * 4;
        size_t o = off + (size_t)r * 64 + c4;
        float4 hv = *(const float4*)(hIn + o);
        float4 d0 = *(const float4*)(dg + o);
        float4 d1 = *(const float4*)(dg + (size_t)NN * 64 + o);
        float4 d2 = *(const float4*)(dg + (size_t)2 * NN * 64 + o);
        hv.x += d0.x + d1.x + d2.x;
        hv.y += d0.y + d1.y + d2.y;
        hv.z += d0.z + d1.z + d2.z;
        hv.w += d0.w + d1.w + d2.w;
        *(float4*)&As[r][c4] = hv;
        if (g == 0) *(float4*)(hOut + o) = hv;
    }
    if (last) return;
    stage_B(conv_w1 + (size_t)(lnext * 3 + g) * 4096, Bs, t);
    __syncthreads();
    int cg = t & 15, rg = t >> 4;
    int c0 = cg * 4, r0 = rg * 2;
    float acc0[4] = {0, 0, 0, 0}, acc1[4] = {0, 0, 0, 0};
    gemm_tile(As, Bs, r0, c0, acc0, acc1);
    int n0 = tile * TILE_M;
    store_xg(xg, g, n0 + r0, c0, acc0);
    store_xg(xg, g, n0 + r0 + 1, c0, acc1);
}

// ---------------- aggregation ----------------
__global__ __launch_bounds__(256) void k_agg(
    const int4* __restrict__ edata, const int* __restrict__ base,
    const float* __restrict__ xg, const float* __restrict__ tab,
    float* __restrict__ agg3, int l) {
    const int lane = threadIdx.x & 63;
    int w = blockIdx.x * 4 + (threadIdx.x >> 6); // 0..7199
    int g = w / AT;
    int dst = w - g * AT;
    const int4* ed = edata + graph_off(g);
    int s = base[g * (AT + 1) + dst];
    int e = base[g * (AT + 1) + dst + 1];
    const float* tg = tab + ((size_t)g * C * L * NT) * 64 + (size_t)l * NT * 64;
    const float* xgg = xg + (size_t)g * AT * BS * 64;
    float acc[BS];
    #pragma unroll
    for (int b = 0; b < BS; b++) acc[b] = 0.0f;
    int i = s;
    for (; i + 2 <= e; i += 2) {
        int4 mA = ed[i], mB = ed[i + 1];
        const float* rA = tg + (size_t)mA.y * 64;
        const float* rB = tg + (size_t)mB.y * 64;
        float frA = __int_as_float(mA.z), frB = __int_as_float(mB.z);
        float rA0 = rA[lane], rA1 = rA[64 + lane];
        float rB0 = rB[lane], rB1 = rB[64 + lane];
        float wvA = fmaf(frA, rA1 - rA0, rA0);
        float wvB = fmaf(frB, rB1 - rB0, rB0);
        const float* xbA = xgg + (size_t)mA.x * (BS * 64) + lane;
        const float* xbB = xgg + (size_t)mB.x * (BS * 64) + lane;
        #pragma unroll
        for (int b = 0; b < BS; b++) {
            acc[b] = fmaf(xbA[b * 64], wvA, acc[b]);
            acc[b] = fmaf(xbB[b * 64], wvB, acc[b]);
        }
    }
    if (i < e) {
        int4 m = ed[i];
        const float* r = tg + (size_t)m.y * 64;
        float fr = __int_as_float(m.z);
        float r0 = r[lane], r1 = r[64 + lane];
        float wv = fmaf(fr, r1 - r0, r0);
        const float* xb = xgg + (size_t)m.x * (BS * 64) + lane;
        #pragma unroll
        for (int b = 0; b < BS; b++)
            acc[b] = fmaf(xb[b * 64], wv, acc[b]);
    }
    float* ao = agg3 + ((size_t)g * NN + dst) * F + lane;
    #pragma unroll
    for (int b = 0; b < BS; b++) ao[(size_t)b * AT * F] = acc[b];
}

// Readout
__global__ void k_read(const float* __restrict__ h,
                       const float* __restrict__ w1, const float* __restrict__ b1,
                       const float* __restrict__ w2, const float* __restrict__ b2,
                       float* __restrict__ out) {
    int b = blockIdx.x;
    int lane = threadIdx.x & 63;
    int wv = threadIdx.x >> 6;
    __shared__ float part[4];
    float weff = 0.0f;
    #pragma unroll
    for (int j = 0; j < H / 2; j++) weff = fmaf(w1[lane * (H / 2) + j], w2[j], weff);
    float acc = 0.0f;
    for (int i = wv * (M2 / 4); i < (wv + 1) * (M2 / 4); i++)
        acc += h[((size_t)b * AT + M1 + i) * H + lane];
    float v = acc * weff;
    for (int off = 32; off; off >>= 1) v += __shfl_xor(v, off);
    if (lane == 0) part[wv] = v;
    __syncthreads();
    if (threadIdx.x == 0) {
        float bias = b2[0];
        for (int j = 0; j < H / 2; j++) bias = fmaf(b1[j], w2[j], bias);
        out[b] = part[0] + part[1] + part[2] + part[3] + (float)M2 * bias;
    }
}

// ---------------- launcher ----------------
extern "C" void kernel_launch(void* const* d_in, const int* in_sizes, int n_in,
                              void* d_out, int out_size, void* d_ws, size_t ws_size,
                              hipStream_t stream) {
    const int* sites   = (const int*)d_in[0];
    const int* sites_p = (const int*)d_in[1];
    const int* ei1 = (const int*)d_in[2];
    const float* ew1 = (const float*)d_in[3];
    const int* c1 = (const int*)d_in[4];
    const int* ei2 = (const int*)d_in[5];
    const float* ew2 = (const float*)d_in[6];
    const int* c2 = (const int*)d_in[7];
    const int* ei3 = (const int*)d_in[8];
    const float* ew3 = (const float*)d_in[9];
    const int* c3 = (const int*)d_in[10];
    const float* emb_w   = (const float*)d_in[11];
    const float* emb_p_w = (const float*)d_in[12];
    const float* mlp_w1 = (const float*)d_in[13];
    const float* mlp_b1 = (const float*)d_in[14];
    const float* mlp_w2 = (const float*)d_in[15];
    const float* mlp_b2 = (const float*)d_in[16];
    const float* conv_w1 = (const float*)d_in[17];
    const float* conv_w2 = (const float*)d_in[18];
    const float* conv_b2 = (const float*)d_in[19];
    const float* blk_w = (const float*)d_in[20];
    const float* blk_b = (const float*)d_in[21];
    const float* out_w1 = (const float*)d_in[22];
    const float* out_b1 = (const float*)d_in[23];
    const float* out_w2 = (const float*)d_in[24];
    const float* out_b2 = (const float*)d_in[25];

    char* ws = (char*)d_ws;
    float* hA   = (float*)(ws + O_HA);
    float* hB   = (float*)(ws + O_HB);
    float* xg   = (float*)(ws + O_XG);
    float* agg3 = (float*)(ws + O_AGG);
    float* dg   = (float*)(ws + O_DG);
    float* tab  = (float*)(ws + O_TAB);
    int4*  edata = (int4*)(ws + O_EDATA);
    int* ip    = (int*)(ws + O_INT);
    int* deg   = ip + I_DEG;
    int* cur   = ip + I_CUR;
    int* ibase = ip + I_BASE;

    hipMemsetAsync(ip, 0, (size_t)I_ZEND * sizeof(int), stream);

    k_table<<<48 * NT / 4, 256, 0, stream>>>(mlp_w1, mlp_b1, mlp_w2, mlp_b2, tab);
    k_init_h<<<(NN * 64 + 255) / 256, 256, 0, stream>>>(sites, sites_p, emb_w, emb_p_w, hA);
    k_count<<<NBLK, 256, 0, stream>>>(ei1, ei2, ei3, c1, c2, c3, deg);
    k_scan<<<3, 256, 0, stream>>>(deg, ibase);
    k_fill<<<NBLK, 256, 0, stream>>>(ei1, ei2, ei3, c1, c2, c3, ew1, ew2, ew3,
                                     ibase, cur, edata);

    k_lin1t<<<3 * MT, 256, 0, stream>>>(hA, conv_w1, xg, 0);
    float* hcur = hA;
    float* hnxt = hB;
    for (int l = 0; l < L; l++) {
        int last = (l == L - 1) ? 1 : 0;
        k_agg<<<3 * AT / 4, 256, 0, stream>>>(edata, ibase, xg, tab, agg3, l);
        k_layerA<<<3 * MT, 256, 0, stream>>>(agg3, conv_w2, conv_b2, blk_w, blk_b,
                                             dg, l);
        k_lin1f<<<last ? MT : 3 * MT, 256, 0, stream>>>(hcur, hnxt, dg, conv_w1,
                                                        xg, l + 1, last);
        float* tmp = hcur; hcur = hnxt; hnxt = tmp;
    }
    k_read<<<BS, 256, 0, stream>>>(hcur, out_w1, out_b1, out_w2, out_b2, (float*)d_out);
}